// Round 2
// baseline (477.604 us; speedup 1.0000x reference)
//
#include <hip/hip_runtime.h>

#define T 1024         // threads per block (16 waves)
#define EPT 16         // elements per thread (16384 / 1024)
#define ROWLEN 16384
#define NW (T / 64)    // waves per block = 16
#define B1 4096        // pass-1 bins (top 12 bits of ordered key)
#define B2 1024        // pass-2/3 bins (10 bits each)
#define CAP 768        // candidate capacity (expected ~90 for normal data)

// Order-preserving float->uint transform: u(a) < u(b)  <=>  a < b
__device__ __forceinline__ unsigned f2ord(float f) {
    unsigned b = __float_as_uint(f);
    return b ^ ((b & 0x80000000u) ? 0xFFFFFFFFu : 0x80000000u);
}
__device__ __forceinline__ float ord2f(unsigned u) {
    unsigned b = (u & 0x80000000u) ? (u ^ 0x80000000u) : ~u;
    return __uint_as_float(b);
}

// Block-cooperative: find bin b* = max{b : S(b) >= k}, S(b) = sum_{d>=b} hist[d].
// Writes *sh_b = b*, *sh_k = k - S(b*+1)  (count still needed inside bin b*).
// Ends with __syncthreads().
__device__ __forceinline__ void select_bin(const int* hist, int BINS, int k,
                                           int* waveSum, int* sh_b, int* sh_k) {
    const int tid  = threadIdx.x;
    const int lane = tid & 63;
    const int w    = tid >> 6;

    int bpt = (BINS + T - 1) / T;
    int lo  = tid * bpt; if (lo > BINS) lo = BINS;
    int hi  = lo + bpt;  if (hi > BINS) hi = BINS;

    int p = 0;
    for (int d = lo; d < hi; ++d) p += hist[d];

    // inclusive suffix scan within wave (64 lanes)
    int v = p;
    #pragma unroll
    for (int off = 1; off < 64; off <<= 1) {
        int t2 = __shfl_down(v, off);
        if (lane + off < 64) v += t2;
    }
    if (lane == 0) waveSum[w] = v;
    __syncthreads();

    int carry = 0;
    #pragma unroll
    for (int w2 = 0; w2 < NW; ++w2) if (w2 > w) carry += waveSum[w2];

    int P  = v + carry;   // S(lo)
    int Pn = P - p;       // S(hi)
    if (P >= k && Pn < k) {   // unique thread owns the crossing
        int running = Pn;
        for (int d = hi - 1; d >= lo; --d) {
            running += hist[d];
            if (running >= k) {
                *sh_b = d;
                *sh_k = k - (running - hist[d]);
                break;
            }
        }
    }
    __syncthreads();
}

__global__ __launch_bounds__(T, 4) void topk_relu_scatter(
        const float* __restrict__ x, const int* __restrict__ kptr,
        float* __restrict__ out) {
    __shared__ int hist[B1];
    __shared__ int waveSum[NW];
    __shared__ int sh_b, sh_k;
    __shared__ int candCnt, sh_meq, sh_cnt;
    __shared__ unsigned candU[CAP];

    const int tid = threadIdx.x;
    const int row = blockIdx.x;
    const float4* xrow = (const float4*)(x + (size_t)row * ROWLEN);
    float4*       orow = (float4*)(out + (size_t)row * ROWLEN);

    // ---- single global read: 4 x float4 per thread, coalesced ----
    unsigned u[EPT];
    #pragma unroll
    for (int j4 = 0; j4 < EPT / 4; ++j4) {
        float4 v = xrow[tid + T * j4];
        u[4 * j4 + 0] = f2ord(v.x);
        u[4 * j4 + 1] = f2ord(v.y);
        u[4 * j4 + 2] = f2ord(v.z);
        u[4 * j4 + 3] = f2ord(v.w);
    }

    int k = *kptr;   // k = 128, uniform

    // ---- pass 1: 12-bit histogram over full row ----
    #pragma unroll
    for (int i = 0; i < B1 / T; ++i) hist[tid + T * i] = 0;
    if (tid == 0) candCnt = 0;
    __syncthreads();
    #pragma unroll
    for (int j = 0; j < EPT; ++j) atomicAdd(&hist[u[j] >> 20], 1);
    __syncthreads();
    select_bin(hist, B1, k, waveSum, &sh_b, &sh_k);
    const unsigned b1 = (unsigned)sh_b; k = sh_k;

    // ---- collect candidates sharing the pass-1 bin ----
    #pragma unroll
    for (int j = 0; j < EPT; ++j) {
        if ((u[j] >> 20) == b1) {
            int p = atomicAdd(&candCnt, 1);
            if (p < CAP) candU[p] = u[j];
        }
    }
    __syncthreads();
    const int m = candCnt;   // uniform

    unsigned ustar; int t_eq;
    if (m <= CAP) {
        // ---- fast path: passes 2/3 over <=768 candidates, 10+10 bits ----
        #pragma unroll
        for (int i = 0; i < B2 / T; ++i) hist[tid + T * i] = 0;
        __syncthreads();
        if (tid < m) atomicAdd(&hist[(candU[tid] >> 10) & 0x3FFu], 1);
        __syncthreads();
        select_bin(hist, B2, k, waveSum, &sh_b, &sh_k);
        const unsigned pref22 = (b1 << 10) | (unsigned)sh_b; k = sh_k;

        for (int i = 0; i < B2 / T; ++i) hist[tid + T * i] = 0;
        __syncthreads();
        if (tid < m) {
            unsigned c = candU[tid];
            if ((c >> 10) == pref22) atomicAdd(&hist[c & 0x3FFu], 1);
        }
        __syncthreads();
        select_bin(hist, B2, k, waveSum, &sh_b, &sh_k);
        ustar = (pref22 << 10) | (unsigned)sh_b;
        t_eq  = sh_k;
    } else {
        // ---- fallback (exact for adversarial data): from registers ----
        #pragma unroll
        for (int i = 0; i < B1 / T; ++i) hist[tid + T * i] = 0;
        __syncthreads();
        #pragma unroll
        for (int j = 0; j < EPT; ++j)
            if ((u[j] >> 20) == b1) atomicAdd(&hist[(u[j] >> 8) & 0xFFFu], 1);
        __syncthreads();
        select_bin(hist, B1, k, waveSum, &sh_b, &sh_k);
        const unsigned pref24 = (b1 << 12) | (unsigned)sh_b; k = sh_k;

        for (int i = tid; i < 256; i += T) hist[i] = 0;
        __syncthreads();
        #pragma unroll
        for (int j = 0; j < EPT; ++j)
            if ((u[j] >> 8) == pref24) atomicAdd(&hist[u[j] & 0xFFu], 1);
        __syncthreads();
        select_bin(hist, 256, k, waveSum, &sh_b, &sh_k);
        ustar = (pref24 << 8) | (unsigned)sh_b;
        t_eq  = sh_k;
    }

    // ---- tie resolution ----
    if (tid == 0) sh_meq = 0;
    __syncthreads();
    int local = 0;
    #pragma unroll
    for (int j = 0; j < EPT; ++j) local += (u[j] == ustar);
    if (local) atomicAdd(&sh_meq, local);
    __syncthreads();
    const int meq = sh_meq;

    int idxcut;
    if (t_eq >= meq) {
        idxcut = ROWLEN;        // accept all equals (the overwhelmingly common case)
    } else {
        // rare: exact duplicates straddle the cut -> block-parallel binary
        // search for smallest c with |{j : u_j == ustar, idx_j <= c}| >= t_eq
        int lo = 0, hi = ROWLEN - 1;
        while (lo < hi) {
            int mid = (lo + hi) >> 1;
            if (tid == 0) sh_cnt = 0;
            __syncthreads();
            int c2 = 0;
            #pragma unroll
            for (int j = 0; j < EPT; ++j) {
                int idx = 4 * (tid + T * (j >> 2)) + (j & 3);
                c2 += (u[j] == ustar && idx <= mid);
            }
            if (c2) atomicAdd(&sh_cnt, c2);
            __syncthreads();
            int cnt = sh_cnt;
            __syncthreads();    // protect sh_cnt before next re-zero
            if (cnt >= t_eq) hi = mid; else lo = mid + 1;
        }
        idxcut = lo;
    }

    // ---- single global write: decode regs, ReLU, dense store ----
    #pragma unroll
    for (int j4 = 0; j4 < EPT / 4; ++j4) {
        float4 o;
        float* op = &o.x;
        #pragma unroll
        for (int c = 0; c < 4; ++c) {
            unsigned uu = u[4 * j4 + c];
            int idx = 4 * (tid + T * j4) + c;
            bool sel = (uu > ustar) || (uu == ustar && idx <= idxcut);
            float xv = ord2f(uu);
            op[c] = (sel && xv > 0.0f) ? xv : 0.0f;
        }
        orow[tid + T * j4] = o;
    }
}

extern "C" void kernel_launch(void* const* d_in, const int* in_sizes, int n_in,
                              void* d_out, int out_size, void* d_ws, size_t ws_size,
                              hipStream_t stream) {
    const float* x    = (const float*)d_in[0];
    const int*   kptr = (const int*)d_in[1];
    float*       out  = (float*)d_out;
    int rows = in_sizes[0] / ROWLEN;   // 4096
    topk_relu_scatter<<<rows, T, 0, stream>>>(x, kptr, out);
}